// Round 8
// baseline (475.235 us; speedup 1.0000x reference)
//
#include <hip/hip_runtime.h>
#include <hip/hip_bf16.h>
#include <hip/hip_cooperative_groups.h>
#include <math.h>

namespace cg = cooperative_groups;

typedef __bf16 bf16x8 __attribute__((ext_vector_type(8)));
typedef __bf16 bf16x4 __attribute__((ext_vector_type(4)));
typedef float f32x4 __attribute__((ext_vector_type(4)));

#define N_TOK 4096
#define EDIM 512
#define NHEAD 8
#define HD 64
#define LDQKV 1536
#define LDCOMB 896
#define NBIN 100
#define SPLITK 8
#define BK 64
#define NWORK (64 * NHEAD * SPLITK)

// prep unit partition
#define NU_CVT 3264
#define NU_TC 64
#define NU_ADD 128
#define NU_TV 200
#define NU_PREP (NU_CVT + NU_TC + NU_ADD + NU_TV + 1)

struct Params {
    const float* x; const int* dmask; const int* steps; const float* status;
    const float* w_in; const float* b_in; const float* w_out; const float* b_out;
    const float* w_mlp; const float* b_mlp; const float* gamma; const float* beta;
    float* out;
    __bf16* x_bf; __bf16* wqkv; __bf16* wmlp; __bf16* woutT; __bf16* weff;
    __bf16* qkv; __bf16* ks; __bf16* vt; __bf16* ctx;
    float* h; int* perm; int* sstep; int* binst; __bf16* po; float* pl;
    float* add2; float* tv; int* workctr; int* bs_row; int* qinfo;
};

union SmemU {
    struct { float T[64][65]; int hist[NBIN]; int offs[NBIN]; float sn[128]; float cs[128]; } prep;
    struct { __bf16 As[128][40]; __bf16 Bs[128][40]; } gemm;
    struct { __bf16 T[64][72]; int pr[64]; } gather;
    struct { __bf16 Ks[64][72]; __bf16 Vs[64][72]; __bf16 Ps[64][72]; int item; } attn;
};

__device__ __forceinline__ void gemm_core(const __bf16* __restrict__ A, int lda,
                                          const __bf16* __restrict__ B, int ldb,
                                          int bm, int bn, int K, int tid,
                                          __bf16 (&As)[128][40], __bf16 (&Bs)[128][40],
                                          f32x4 (&acc)[4][4]) {
    const int wave = tid >> 6, lane = tid & 63;
    const int wm = (wave >> 1) * 64, wn = (wave & 1) * 64;
    const int lr = lane & 15, lq = lane >> 4;
    for (int k0 = 0; k0 < K; k0 += 32) {
        __syncthreads();
        #pragma unroll
        for (int c = tid; c < 512; c += 256) {
            const int row = c >> 2, k8 = (c & 3) * 8;
            *(bf16x8*)&As[row][k8] = *(const bf16x8*)&A[(size_t)(bm + row) * lda + k0 + k8];
            *(bf16x8*)&Bs[row][k8] = *(const bf16x8*)&B[(size_t)(bn + row) * ldb + k0 + k8];
        }
        __syncthreads();
        bf16x8 af[4], bfr[4];
        #pragma unroll
        for (int i = 0; i < 4; i++) {
            af[i]  = *(const bf16x8*)&As[wm + i * 16 + lr][lq * 8];
            bfr[i] = *(const bf16x8*)&Bs[wn + i * 16 + lr][lq * 8];
        }
        #pragma unroll
        for (int i = 0; i < 4; i++)
            #pragma unroll
            for (int j = 0; j < 4; j++)
                acc[i][j] = __builtin_amdgcn_mfma_f32_16x16x32_bf16(af[i], bfr[j], acc[i][j], 0, 0, 0);
    }
}

__global__ __launch_bounds__(256) void mega_kernel(Params p) {
    __shared__ __align__(16) SmemU sm;
    cg::grid_group grid = cg::this_grid();
    const int tid = threadIdx.x;
    const int NB = gridDim.x;
    const int wave = tid >> 6, lane = tid & 63;
    const int lr = lane & 15, lq = lane >> 4;

    // ================= P0: prep =================
    for (int u = blockIdx.x; u < NU_PREP; u += NB) {
        __syncthreads();
        if (u < NU_CVT) {
            // fp32 -> bf16: x, w_in, w_mlp
            int i = u * 256 + tid;
            const int n0 = N_TOK * EDIM / 4;
            const int n1 = 3 * EDIM * EDIM / 4;
            const float* src; __bf16* dst;
            if (i < n0)           { src = p.x; dst = p.x_bf; }
            else if (i < n0 + n1) { i -= n0; src = p.w_in; dst = p.wqkv; }
            else                  { i -= n0 + n1; src = p.w_mlp; dst = p.wmlp; }
            const float4 v = ((const float4*)src)[i];
            bf16x4 o;
            o[0] = (__bf16)v.x; o[1] = (__bf16)v.y; o[2] = (__bf16)v.z; o[3] = (__bf16)v.w;
            ((bf16x4*)dst)[i] = o;
        } else if (u < NU_CVT + NU_TC) {
            // w_out transpose + cvt
            const int b2 = u - NU_CVT;
            const int m0 = (b2 >> 3) * 64, k0 = (b2 & 7) * 64;
            const int row = tid >> 2, c4 = (tid & 3) * 16;
            #pragma unroll
            for (int i = 0; i < 4; i++) {
                const float4 v = *(const float4*)&p.w_out[(size_t)(m0 + row) * EDIM + k0 + c4 + i * 4];
                sm.prep.T[row][c4 + i * 4 + 0] = v.x;
                sm.prep.T[row][c4 + i * 4 + 1] = v.y;
                sm.prep.T[row][c4 + i * 4 + 2] = v.z;
                sm.prep.T[row][c4 + i * 4 + 3] = v.w;
            }
            __syncthreads();
            const int kr = tid >> 2, m16 = (tid & 3) * 16;
            bf16x8 o0, o1;
            #pragma unroll
            for (int i = 0; i < 8; i++) o0[i] = (__bf16)sm.prep.T[m16 + i][kr];
            #pragma unroll
            for (int i = 0; i < 8; i++) o1[i] = (__bf16)sm.prep.T[m16 + 8 + i][kr];
            *(bf16x8*)&p.woutT[(size_t)(k0 + kr) * EDIM + m0 + m16] = o0;
            *(bf16x8*)&p.woutT[(size_t)(k0 + kr) * EDIM + m0 + m16 + 8] = o1;
        } else if (u < NU_CVT + NU_TC + NU_ADD) {
            // add2[m][j] = status[m].w_mlp[j,512:640] + mlp_b[j] + w_mlp[j,:512].b_out
            const int j = (u - NU_CVT - NU_TC) * 4 + wave;
            const float* wr = p.w_mlp + (size_t)j * LDCOMB;
            const int k8 = lane * 8;
            const float4 wa = *(const float4*)&wr[k8], wb = *(const float4*)&wr[k8 + 4];
            const float4 oa = *(const float4*)&p.b_out[k8], ob = *(const float4*)&p.b_out[k8 + 4];
            float b = wa.x * oa.x + wa.y * oa.y + wa.z * oa.z + wa.w * oa.w +
                      wb.x * ob.x + wb.y * ob.y + wb.z * ob.z + wb.w * ob.w;
            const int c2 = lane * 2;
            const float w0 = wr[EDIM + c2], w1 = wr[EDIM + c2 + 1];
            float s0 = p.status[c2] * w0 + p.status[c2 + 1] * w1;
            float s1 = p.status[128 + c2] * w0 + p.status[129 + c2] * w1;
            #pragma unroll
            for (int m = 1; m < 64; m <<= 1) {
                b += __shfl_xor(b, m);
                s0 += __shfl_xor(s0, m);
                s1 += __shfl_xor(s1, m);
            }
            if (lane == 0) {
                const float bb = b + p.b_mlp[j];
                p.add2[j] = s0 + bb;
                p.add2[EDIM + j] = s1 + bb;
            }
        } else if (u < NU_CVT + NU_TC + NU_ADD + NU_TV) {
            // tv[st][j] = time_enc[st] . w_mlp[j,640:896]
            const int b2 = u - NU_CVT - NU_TC - NU_ADD;
            const int st = b2 >> 1, jg = b2 & 1;
            if (tid < 128) {
                const float div = expf((float)(2 * tid) * (-9.210340371976184f / 256.0f));
                const float ang = (float)st * div;
                sm.prep.sn[tid] = sinf(ang);
                sm.prep.cs[tid] = cosf(ang);
            }
            __syncthreads();
            const int j = jg * 256 + tid;
            const float* wr = p.w_mlp + (size_t)j * LDCOMB + 640;
            float acc = 0.f;
            #pragma unroll 4
            for (int q = 0; q < 128; q++)
                acc += sm.prep.sn[q] * wr[2 * q] + sm.prep.cs[q] * wr[2 * q + 1];
            p.tv[st * EDIM + j] = acc;
        } else {
            // counting sort + bs_row + qinfo + work counter
            if (tid == 0) p.workctr[0] = 0;
            if (tid < NBIN) sm.prep.hist[tid] = 0;
            __syncthreads();
            for (int i = tid; i < N_TOK; i += 256)
                atomicAdd(&sm.prep.hist[min(max(p.steps[i], 0), NBIN - 1)], 1);
            __syncthreads();
            if (tid == 0) {
                int acc = 0;
                for (int s = 0; s < NBIN; s++) { sm.prep.offs[s] = acc; acc += sm.prep.hist[s]; }
            }
            __syncthreads();
            if (tid < NBIN) {
                const int v = sm.prep.offs[tid];
                p.binst[tid] = v;
                sm.prep.hist[tid] = v;   // LDS copy of bin_start (offs gets mutated)
            }
            __syncthreads();
            for (int i = tid; i < N_TOK; i += 256) {
                const int s = min(max(p.steps[i], 0), NBIN - 1);
                const int pos = atomicAdd(&sm.prep.offs[s], 1);
                p.perm[pos] = i;
                p.sstep[pos] = s;
            }
            __syncthreads();
            for (int q = tid; q < N_TOK; q += 256)
                p.bs_row[q] = sm.prep.hist[p.sstep[q]];
            __syncthreads();
            for (int qt = tid; qt < 64; qt += 256) {
                p.qinfo[qt * 2] = p.bs_row[qt * 64] & ~(BK - 1);
                p.qinfo[qt * 2 + 1] = p.bs_row[qt * 64 + 63];
            }
        }
    }
    grid.sync();

    // ================= P1: qkv GEMM (384) + weff GEMM (16) =================
    for (int u = blockIdx.x; u < 400; u += NB) {
        f32x4 acc[4][4] = {};
        if (u < 384) {
            const int bm = (u & 31) * 128, bn = (u >> 5) * 128;
            gemm_core(p.x_bf, EDIM, p.wqkv, EDIM, bm, bn, EDIM, tid, sm.gemm.As, sm.gemm.Bs, acc);
            const int wm = (wave >> 1) * 64, wn = (wave & 1) * 64;
            #pragma unroll
            for (int i = 0; i < 4; i++)
                #pragma unroll
                for (int j = 0; j < 4; j++) {
                    const int col = bn + wn + j * 16 + lr;
                    const float bv = p.b_in[col];
                    #pragma unroll
                    for (int r = 0; r < 4; r++)
                        p.qkv[(size_t)(bm + wm + i * 16 + lq * 4 + r) * LDQKV + col] =
                            (__bf16)(acc[i][j][r] + bv);
                }
        } else {
            const int b2 = u - 384;
            const int bm = (b2 & 3) * 128, bn = (b2 >> 2) * 128;
            gemm_core(p.wmlp, LDCOMB, p.woutT, EDIM, bm, bn, EDIM, tid, sm.gemm.As, sm.gemm.Bs, acc);
            const int wm = (wave >> 1) * 64, wn = (wave & 1) * 64;
            #pragma unroll
            for (int i = 0; i < 4; i++)
                #pragma unroll
                for (int j = 0; j < 4; j++) {
                    const int col = bn + wn + j * 16 + lr;
                    #pragma unroll
                    for (int r = 0; r < 4; r++)
                        p.weff[(size_t)(bm + wm + i * 16 + lq * 4 + r) * EDIM + col] =
                            (__bf16)acc[i][j][r];
                }
        }
        __syncthreads();
    }
    grid.sync();

    // ================= P2: gather sorted Q (prescaled) / K / V^T =================
    for (int u = blockIdx.x; u < 512; u += NB) {
        __syncthreads();
        const int n0 = (u & 63) * 64, h = u >> 6;
        if (tid < 64) sm.gather.pr[tid] = p.perm[n0 + tid];
        __syncthreads();
        const float SC = 0.125f * 1.44269504f;
        #pragma unroll
        for (int c = tid; c < 512; c += 256) {
            const int r = c >> 3, d8 = (c & 7) * 8;
            const size_t src = (size_t)sm.gather.pr[r] * LDQKV + h * HD + d8;
            bf16x8 q = *(const bf16x8*)&p.qkv[src];
            #pragma unroll
            for (int j = 0; j < 8; j++) q[j] = (__bf16)((float)q[j] * SC);
            *(bf16x8*)&p.x_bf[(size_t)(n0 + r) * EDIM + h * HD + d8] = q;  // qs aliases x_bf
            *(bf16x8*)&p.ks[(size_t)(n0 + r) * EDIM + h * HD + d8] =
                *(const bf16x8*)&p.qkv[src + EDIM];
            *(bf16x8*)&sm.gather.T[r][d8] = *(const bf16x8*)&p.qkv[src + 2 * EDIM];
        }
        __syncthreads();
        #pragma unroll
        for (int c = tid; c < 512; c += 256) {
            const int d = c & 63, k8 = (c >> 6) * 8;
            bf16x8 v;
            #pragma unroll
            for (int j = 0; j < 8; j++) v[j] = sm.gather.T[k8 + j][d];
            *(bf16x8*)&p.vt[(size_t)(h * HD + d) * N_TOK + n0 + k8] = v;
        }
    }
    grid.sync();

    // ================= P3: attention (work queue, LPT order) =================
    {
        const int r0 = tid >> 3, r1 = r0 + 32, k8 = (tid & 7) * 8;
        const __bf16* qs = p.x_bf;
        for (;;) {
            __syncthreads();
            if (tid == 0) sm.attn.item = atomicAdd(p.workctr, 1);
            __syncthreads();
            const int item = sm.attn.item;
            if (item >= NWORK) break;

            const int qtile = item >> 6;
            const int h = (item >> 3) & 7;
            const int ck = item & 7;
            const int qbase = qtile * 64 + wave * 16;

            const int kt0 = p.qinfo[qtile * 2];
            const int bs_blockmax = p.qinfo[qtile * 2 + 1];
            const int nt = (N_TOK - kt0) / BK;
            const int kta = kt0 + ((nt * ck) / SPLITK) * BK;
            const int ktb = kt0 + ((nt * (ck + 1)) / SPLITK) * BK;

            bf16x8 aq[2];
            {
                const __bf16* qrow = qs + (size_t)(qbase + lr) * EDIM + h * HD;
                aq[0] = *(const bf16x8*)&qrow[lq * 8];
                aq[1] = *(const bf16x8*)&qrow[32 + lq * 8];
            }
            int bs_r[4];
            #pragma unroll
            for (int r = 0; r < 4; r++) bs_r[r] = p.bs_row[qbase + lq * 4 + r];

            float l_i[4] = {0.f, 0.f, 0.f, 0.f};
            f32x4 o[4] = {};

            const __bf16* kbase = p.ks + h * HD;
            const __bf16* vbase = p.vt + (size_t)h * HD * N_TOK;

            bf16x8 kr0, kr1, vr0, vr1;
            if (kta < ktb) {
                kr0 = *(const bf16x8*)&kbase[(size_t)(kta + r0) * EDIM + k8];
                kr1 = *(const bf16x8*)&kbase[(size_t)(kta + r1) * EDIM + k8];
                vr0 = *(const bf16x8*)&vbase[(size_t)r0 * N_TOK + kta + k8];
                vr1 = *(const bf16x8*)&vbase[(size_t)r1 * N_TOK + kta + k8];
            }

            for (int kt = kta; kt < ktb; kt += BK) {
                __syncthreads();
                *(bf16x8*)&sm.attn.Ks[r0][k8] = kr0;
                *(bf16x8*)&sm.attn.Ks[r1][k8] = kr1;
                *(bf16x8*)&sm.attn.Vs[r0][k8] = vr0;
                *(bf16x8*)&sm.attn.Vs[r1][k8] = vr1;
                __syncthreads();
                if (kt + BK < ktb) {
                    kr0 = *(const bf16x8*)&kbase[(size_t)(kt + BK + r0) * EDIM + k8];
                    kr1 = *(const bf16x8*)&kbase[(size_t)(kt + BK + r1) * EDIM + k8];
                    vr0 = *(const bf16x8*)&vbase[(size_t)r0 * N_TOK + kt + BK + k8];
                    vr1 = *(const bf16x8*)&vbase[(size_t)r1 * N_TOK + kt + BK + k8];
                }

                f32x4 s[4];
                #pragma unroll
                for (int t = 0; t < 4; t++) {
                    bf16x8 b0 = *(const bf16x8*)&sm.attn.Ks[t * 16 + lr][lq * 8];
                    bf16x8 b1 = *(const bf16x8*)&sm.attn.Ks[t * 16 + lr][32 + lq * 8];
                    f32x4 a = {};
                    a = __builtin_amdgcn_mfma_f32_16x16x32_bf16(aq[0], b0, a, 0, 0, 0);
                    a = __builtin_amdgcn_mfma_f32_16x16x32_bf16(aq[1], b1, a, 0, 0, 0);
                    s[t] = a;
                }
                if (kt < bs_blockmax) {
                    #pragma unroll
                    for (int t = 0; t < 4; t++) {
                        const int col = kt + t * 16 + lr;
                        #pragma unroll
                        for (int r = 0; r < 4; r++)
                            if (col < bs_r[r]) s[t][r] = -1e9f;
                    }
                }
                #pragma unroll
                for (int t = 0; t < 4; t++) {
                    #pragma unroll
                    for (int r = 0; r < 4; r++) {
                        const float pr = exp2f(s[t][r]);
                        l_i[r] += pr;
                        sm.attn.Ps[wave * 16 + lq * 4 + r][t * 16 + lr] = (__bf16)pr;
                    }
                }
                #pragma unroll
                for (int ks2 = 0; ks2 < 2; ks2++) {
                    bf16x8 ap = *(const bf16x8*)&sm.attn.Ps[wave * 16 + lr][ks2 * 32 + lq * 8];
                    #pragma unroll
                    for (int dt = 0; dt < 4; dt++) {
                        bf16x8 bv = *(const bf16x8*)&sm.attn.Vs[dt * 16 + lr][ks2 * 32 + lq * 8];
                        o[dt] = __builtin_amdgcn_mfma_f32_16x16x32_bf16(ap, bv, o[dt], 0, 0, 0);
                    }
                }
            }

            #pragma unroll
            for (int r = 0; r < 4; r++) {
                float v = l_i[r];
                v += __shfl_xor(v, 1);
                v += __shfl_xor(v, 2);
                v += __shfl_xor(v, 4);
                v += __shfl_xor(v, 8);
                l_i[r] = v;
            }
            __bf16* pob = p.po + (((size_t)(ck * NHEAD + h) * N_TOK) + qbase) * HD;
            #pragma unroll
            for (int dt = 0; dt < 4; dt++)
                #pragma unroll
                for (int r = 0; r < 4; r++)
                    pob[(lq * 4 + r) * HD + dt * 16 + lr] = (__bf16)o[dt][r];
            if (lr == 0) {
                #pragma unroll
                for (int r = 0; r < 4; r++)
                    p.pl[(size_t)(ck * NHEAD + h) * N_TOK + qbase + lq * 4 + r] = l_i[r];
            }
        }
    }
    grid.sync();

    // ================= P4: combine partials -> ctx (original order) =================
    for (int u = blockIdx.x; u < (N_TOK * EDIM) / 256; u += NB) {
        const int e = u * 256 + tid;
        const int q = e >> 9;
        const int col = e & 511;
        const int h = col >> 6, d = col & 63;
        float s = 0.f, l = 0.f;
        #pragma unroll
        for (int c = 0; c < SPLITK; c++) {
            s += (float)p.po[(((size_t)(c * NHEAD + h) * N_TOK) + q) * HD + d];
            l += p.pl[(size_t)(c * NHEAD + h) * N_TOK + q];
        }
        p.ctx[(size_t)p.perm[q] * EDIM + col] = (__bf16)(s / l);
    }
    grid.sync();

    // ================= P5: h = ctx @ weff^T + add2[dmask] + tv[step] =================
    for (int u = blockIdx.x; u < 128; u += NB) {
        __syncthreads();
        f32x4 acc[4][4] = {};
        const int bm = (u & 31) * 128, bn = (u >> 5) * 128;
        gemm_core(p.ctx, EDIM, p.weff, EDIM, bm, bn, EDIM, tid, sm.gemm.As, sm.gemm.Bs, acc);
        const int wm = (wave >> 1) * 64, wn = (wave & 1) * 64;
        int dmr[4][4], str[4][4];
        #pragma unroll
        for (int i = 0; i < 4; i++)
            #pragma unroll
            for (int r = 0; r < 4; r++) {
                const int row = bm + wm + i * 16 + lq * 4 + r;
                dmr[i][r] = p.dmask[row];
                str[i][r] = min(max(p.steps[row], 0), NBIN - 1);
            }
        #pragma unroll
        for (int i = 0; i < 4; i++)
            #pragma unroll
            for (int j = 0; j < 4; j++) {
                const int col = bn + wn + j * 16 + lr;
                #pragma unroll
                for (int r = 0; r < 4; r++) {
                    const int row = bm + wm + i * 16 + lq * 4 + r;
                    p.h[(size_t)row * EDIM + col] = acc[i][j][r]
                        + p.add2[dmr[i][r] * EDIM + col] + p.tv[str[i][r] * EDIM + col];
                }
            }
    }
    grid.sync();

    // ================= P6: LayerNorm + ReLU + residual =================
    for (int u = blockIdx.x; u < N_TOK / 4; u += NB) {
        const int row = u * 4 + wave;
        const float* hr = p.h + (size_t)row * EDIM;
        float4 v0 = ((const float4*)hr)[lane];
        float4 v1 = ((const float4*)hr)[64 + lane];
        float sum = v0.x + v0.y + v0.z + v0.w + v1.x + v1.y + v1.z + v1.w;
        float sq = v0.x * v0.x + v0.y * v0.y + v0.z * v0.z + v0.w * v0.w +
                   v1.x * v1.x + v1.y * v1.y + v1.z * v1.z + v1.w * v1.w;
        #pragma unroll
        for (int m = 1; m < 64; m <<= 1) {
            sum += __shfl_xor(sum, m);
            sq  += __shfl_xor(sq, m);
        }
        const float mean = sum * (1.0f / EDIM);
        const float var = sq * (1.0f / EDIM) - mean * mean;
        const float rstd = rsqrtf(var + 1e-5f);
        const float* xr = p.x + (size_t)row * EDIM;
        float* orow = p.out + (size_t)row * EDIM;
        #pragma unroll
        for (int half = 0; half < 2; half++) {
            const float4 v = half ? v1 : v0;
            const int cb = half * 256 + lane * 4;
            const float* vp = (const float*)&v;
            float4 res;
            float tmp[4];
            #pragma unroll
            for (int i = 0; i < 4; i++) {
                const int c = cb + i;
                float t = (vp[i] - mean) * rstd * p.gamma[c] + p.beta[c];
                t = fmaxf(t, 0.f);
                tmp[i] = xr[c] + t;
            }
            res.x = tmp[0]; res.y = tmp[1]; res.z = tmp[2]; res.w = tmp[3];
            ((float4*)orow)[cb >> 2] = res;
        }
    }
}

// ---------------- launch ----------------
extern "C" void kernel_launch(void* const* d_in, const int* in_sizes, int n_in,
                              void* d_out, int out_size, void* d_ws, size_t ws_size,
                              hipStream_t stream) {
    char* ws = (char*)d_ws;
    size_t off = 0;
    auto alloc = [&](size_t bytes) {
        void* ptr = ws + off;
        off = (off + bytes + 255) & ~(size_t)255;
        return ptr;
    };
    Params p;
    p.x      = (const float*)d_in[0];
    p.dmask  = (const int*)d_in[1];
    p.steps  = (const int*)d_in[2];
    p.status = (const float*)d_in[3];
    p.w_in   = (const float*)d_in[4];
    p.b_in   = (const float*)d_in[5];
    p.w_out  = (const float*)d_in[6];
    p.b_out  = (const float*)d_in[7];
    p.w_mlp  = (const float*)d_in[8];
    p.b_mlp  = (const float*)d_in[9];
    p.gamma  = (const float*)d_in[10];
    p.beta   = (const float*)d_in[11];
    p.out    = (float*)d_out;

    p.x_bf   = (__bf16*)alloc((size_t)N_TOK * EDIM * 2);      // also qs after P2
    p.wqkv   = (__bf16*)alloc((size_t)3 * EDIM * EDIM * 2);
    p.wmlp   = (__bf16*)alloc((size_t)EDIM * LDCOMB * 2);
    p.woutT  = (__bf16*)alloc((size_t)EDIM * EDIM * 2);
    p.weff   = (__bf16*)alloc((size_t)EDIM * EDIM * 2);
    p.qkv    = (__bf16*)alloc((size_t)N_TOK * LDQKV * 2);
    p.ks     = (__bf16*)alloc((size_t)N_TOK * EDIM * 2);
    p.vt     = (__bf16*)alloc((size_t)EDIM * N_TOK * 2);
    p.ctx    = (__bf16*)alloc((size_t)N_TOK * EDIM * 2);
    p.h      = (float*)alloc((size_t)N_TOK * EDIM * 4);
    p.perm   = (int*)alloc(N_TOK * 4);
    p.sstep  = (int*)alloc(N_TOK * 4);
    p.binst  = (int*)alloc(NBIN * 4);
    p.po     = (__bf16*)alloc((size_t)SPLITK * NHEAD * N_TOK * HD * 2);
    p.pl     = (float*)alloc((size_t)SPLITK * NHEAD * N_TOK * 4);
    p.add2   = (float*)alloc(2 * EDIM * 4);
    p.tv     = (float*)alloc((size_t)NBIN * EDIM * 4);
    p.workctr= (int*)alloc(256);
    p.bs_row = (int*)alloc(N_TOK * 4);
    p.qinfo  = (int*)alloc(128 * 4);

    int nb = 0;
    if (hipOccupancyMaxActiveBlocksPerMultiprocessor(&nb, mega_kernel, 256, 0) != hipSuccess || nb < 1)
        nb = 4;
    int G = nb * 256;
    if (G > 4096) G = 4096;

    void* args[] = { &p };
    hipLaunchCooperativeKernel(reinterpret_cast<void*>(mega_kernel),
                               dim3(G), dim3(256), args, 0, stream);
}

// Round 9
// 229.755 us; speedup vs baseline: 2.0684x; 2.0684x over previous
//
#include <hip/hip_runtime.h>
#include <hip/hip_bf16.h>
#include <math.h>

typedef __bf16 bf16x8 __attribute__((ext_vector_type(8)));
typedef __bf16 bf16x4 __attribute__((ext_vector_type(4)));
typedef float f32x4 __attribute__((ext_vector_type(4)));

#define N_TOK 4096
#define EDIM 512
#define NHEAD 8
#define HD 64
#define LDQKV 1536
#define LDCOMB 896
#define NBIN 100
#define SPLITK 8
#define BK 64
#define BQ 128

// prep block partition
#define NU_CVT 3264
#define NU_TC 64
#define NU_ADD 128
#define NU_TMAT 128
#define NB_PREP (NU_CVT + NU_TC + NU_ADD + NU_TMAT + 1)

// ---------------- prep: cvt + w_out^T + add2 + time-matrix + sort/plan ----------------
__global__ __launch_bounds__(256) void prep_kernel(
    const float* __restrict__ x, const float* __restrict__ w_in,
    const float* __restrict__ w_mlp, const float* __restrict__ w_out,
    const float* __restrict__ status, const float* __restrict__ out_b,
    const float* __restrict__ mlp_b, const int* __restrict__ steps,
    __bf16* __restrict__ x_bf, __bf16* __restrict__ wqkv_bf,
    __bf16* __restrict__ wmlp_bf, __bf16* __restrict__ woutT_bf,
    float* __restrict__ add2, __bf16* __restrict__ tmat,
    int* __restrict__ perm, int* __restrict__ sstep,
    int* __restrict__ bs_row, int* __restrict__ qinfo) {
    __shared__ float T[64][65];
    __shared__ int hist[NBIN];
    __shared__ int offs[NBIN];
    const int bid = blockIdx.x;
    const int tid = threadIdx.x;
    const int wave = tid >> 6, lane = tid & 63;

    if (bid < NU_CVT) {
        // fp32 -> bf16: x, w_in, w_mlp
        int i = bid * 256 + tid;
        const int n0 = N_TOK * EDIM / 4;
        const int n1 = 3 * EDIM * EDIM / 4;
        const float* src; __bf16* dst;
        if (i < n0)           { src = x; dst = x_bf; }
        else if (i < n0 + n1) { i -= n0; src = w_in; dst = wqkv_bf; }
        else                  { i -= n0 + n1; src = w_mlp; dst = wmlp_bf; }
        const float4 v = ((const float4*)src)[i];
        bf16x4 o;
        o[0] = (__bf16)v.x; o[1] = (__bf16)v.y; o[2] = (__bf16)v.z; o[3] = (__bf16)v.w;
        ((bf16x4*)dst)[i] = o;
    } else if (bid < NU_CVT + NU_TC) {
        // transpose+cvt w_out -> woutT[k][m]
        const int b2 = bid - NU_CVT;
        const int m0 = (b2 >> 3) * 64, k0 = (b2 & 7) * 64;
        const int row = tid >> 2, c4 = (tid & 3) * 16;
        #pragma unroll
        for (int i = 0; i < 4; i++) {
            const float4 v = *(const float4*)&w_out[(size_t)(m0 + row) * EDIM + k0 + c4 + i * 4];
            T[row][c4 + i * 4 + 0] = v.x;
            T[row][c4 + i * 4 + 1] = v.y;
            T[row][c4 + i * 4 + 2] = v.z;
            T[row][c4 + i * 4 + 3] = v.w;
        }
        __syncthreads();
        const int kr = tid >> 2, m16 = (tid & 3) * 16;
        bf16x8 o0, o1;
        #pragma unroll
        for (int i = 0; i < 8; i++) o0[i] = (__bf16)T[m16 + i][kr];
        #pragma unroll
        for (int i = 0; i < 8; i++) o1[i] = (__bf16)T[m16 + 8 + i][kr];
        *(bf16x8*)&woutT_bf[(size_t)(k0 + kr) * EDIM + m0 + m16] = o0;
        *(bf16x8*)&woutT_bf[(size_t)(k0 + kr) * EDIM + m0 + m16 + 8] = o1;
    } else if (bid < NU_CVT + NU_TC + NU_ADD) {
        // add2[m][j] = status[m].w_mlp[j,512:640] + mlp_b[j] + w_mlp[j,:512].b_out
        const int j = (bid - NU_CVT - NU_TC) * 4 + wave;
        const float* wr = w_mlp + (size_t)j * LDCOMB;
        const int k8 = lane * 8;
        const float4 wa = *(const float4*)&wr[k8], wb = *(const float4*)&wr[k8 + 4];
        const float4 oa = *(const float4*)&out_b[k8], ob = *(const float4*)&out_b[k8 + 4];
        float b = wa.x * oa.x + wa.y * oa.y + wa.z * oa.z + wa.w * oa.w +
                  wb.x * ob.x + wb.y * ob.y + wb.z * ob.z + wb.w * ob.w;
        const int c2 = lane * 2;
        const float w0 = wr[EDIM + c2], w1 = wr[EDIM + c2 + 1];
        float s0 = status[c2] * w0 + status[c2 + 1] * w1;
        float s1 = status[128 + c2] * w0 + status[129 + c2] * w1;
        #pragma unroll
        for (int m = 1; m < 64; m <<= 1) {
            b += __shfl_xor(b, m);
            s0 += __shfl_xor(s0, m);
            s1 += __shfl_xor(s1, m);
        }
        if (lane == 0) {
            const float bb = b + mlp_b[j];
            add2[j] = s0 + bb;
            add2[EDIM + j] = s1 + bb;
        }
    } else if (bid < NU_CVT + NU_TC + NU_ADD + NU_TMAT) {
        // bf16 time matrix [128][256] (rows >= 100 padding, never read back via tv)
        const int st = bid - NU_CVT - NU_TC - NU_ADD;
        const int c = tid;
        const int pp = c >> 1;
        const float div = expf((float)(2 * pp) * (-9.210340371976184f / 256.0f));
        const float ang = (float)st * div;
        tmat[st * 256 + c] = (__bf16)((c & 1) ? cosf(ang) : sinf(ang));
    } else {
        // counting sort by step + bs_row + per-qtile plan
        if (tid < NBIN) hist[tid] = 0;
        __syncthreads();
        for (int i = tid; i < N_TOK; i += 256)
            atomicAdd(&hist[min(max(steps[i], 0), NBIN - 1)], 1);
        __syncthreads();
        if (tid == 0) {
            int acc = 0;
            for (int s = 0; s < NBIN; s++) { offs[s] = acc; acc += hist[s]; }
        }
        __syncthreads();
        if (tid < NBIN) hist[tid] = offs[tid];   // immutable copy of bin_start
        __syncthreads();
        for (int i = tid; i < N_TOK; i += 256) {
            const int s = min(max(steps[i], 0), NBIN - 1);
            const int pos = atomicAdd(&offs[s], 1);
            perm[pos] = i;
            sstep[pos] = s;
        }
        __syncthreads();
        for (int q = tid; q < N_TOK; q += 256)
            bs_row[q] = hist[sstep[q]];
        __syncthreads();
        for (int qt = tid; qt < N_TOK / BQ; qt += 256) {
            qinfo[qt * 2] = bs_row[qt * BQ] & ~(BK - 1);
            qinfo[qt * 2 + 1] = bs_row[qt * BQ + BQ - 1];
        }
    }
}

// ---------------- merged GEMMs: qkv (384) + weff (16) + tv (4) ----------------
__global__ __launch_bounds__(256) void gemm2_kernel(const __bf16* __restrict__ x_bf,
                                                    const __bf16* __restrict__ wqkv_bf,
                                                    const float* __restrict__ b_in,
                                                    __bf16* __restrict__ qkv_bf,
                                                    const __bf16* __restrict__ wmlp_bf,
                                                    const __bf16* __restrict__ woutT_bf,
                                                    __bf16* __restrict__ weff_bf,
                                                    const __bf16* __restrict__ tmat,
                                                    float* __restrict__ tv) {
    __shared__ __attribute__((aligned(16))) __bf16 As[128][40];
    __shared__ __attribute__((aligned(16))) __bf16 Bs[128][40];
    const int bid = blockIdx.x;
    const int tid = threadIdx.x;
    const int wave = tid >> 6, lane = tid & 63;
    const int wm = (wave >> 1) * 64, wn = (wave & 1) * 64;
    const int lr = lane & 15, lq = lane >> 4;

    const __bf16 *A, *B;
    int lda, ldb, bm, bn, K, mode;
    if (bid < 384) {
        A = x_bf; lda = EDIM; B = wqkv_bf; ldb = EDIM; K = EDIM; mode = 0;
        bm = (bid & 31) * 128; bn = (bid >> 5) * 128;
    } else if (bid < 400) {
        const int b2 = bid - 384;
        A = wmlp_bf; lda = LDCOMB; B = woutT_bf; ldb = EDIM; K = EDIM; mode = 1;
        bm = (b2 & 3) * 128; bn = (b2 >> 2) * 128;
    } else {
        const int b3 = bid - 400;
        A = tmat; lda = 256; B = wmlp_bf + 640; ldb = LDCOMB; K = 256; mode = 2;
        bm = 0; bn = b3 * 128;
    }

    f32x4 acc[4][4] = {};
    for (int k0 = 0; k0 < K; k0 += 32) {
        __syncthreads();
        #pragma unroll
        for (int c = tid; c < 512; c += 256) {
            const int row = c >> 2, k8 = (c & 3) * 8;
            *(bf16x8*)&As[row][k8] = *(const bf16x8*)&A[(size_t)(bm + row) * lda + k0 + k8];
            *(bf16x8*)&Bs[row][k8] = *(const bf16x8*)&B[(size_t)(bn + row) * ldb + k0 + k8];
        }
        __syncthreads();
        bf16x8 af[4], bfr[4];
        #pragma unroll
        for (int i = 0; i < 4; i++) {
            af[i]  = *(const bf16x8*)&As[wm + i * 16 + lr][lq * 8];
            bfr[i] = *(const bf16x8*)&Bs[wn + i * 16 + lr][lq * 8];
        }
        #pragma unroll
        for (int i = 0; i < 4; i++)
            #pragma unroll
            for (int j = 0; j < 4; j++)
                acc[i][j] = __builtin_amdgcn_mfma_f32_16x16x32_bf16(af[i], bfr[j], acc[i][j], 0, 0, 0);
    }

    #pragma unroll
    for (int i = 0; i < 4; i++) {
        #pragma unroll
        for (int j = 0; j < 4; j++) {
            const int col = bn + wn + j * 16 + lr;
            #pragma unroll
            for (int r = 0; r < 4; r++) {
                const int row = bm + wm + i * 16 + lq * 4 + r;
                if (mode == 0)
                    qkv_bf[(size_t)row * LDQKV + col] = (__bf16)(acc[i][j][r] + b_in[col]);
                else if (mode == 1)
                    weff_bf[(size_t)row * EDIM + col] = (__bf16)acc[i][j][r];
                else if (row < NBIN)
                    tv[(size_t)row * EDIM + col] = acc[i][j][r];
            }
        }
    }
}

// ---------------- gather sorted Q (prescaled), K compact, V^T ----------------
__global__ __launch_bounds__(256) void gather_kernel(const __bf16* __restrict__ qkv,
                                                     const int* __restrict__ perm,
                                                     __bf16* __restrict__ qs,
                                                     __bf16* __restrict__ ks,
                                                     __bf16* __restrict__ vt) {
    __shared__ __attribute__((aligned(16))) __bf16 T[64][72];
    __shared__ int pr[64];
    const int h = blockIdx.y;
    const int n0 = blockIdx.x * 64;
    const int tid = threadIdx.x;
    if (tid < 64) pr[tid] = perm[n0 + tid];
    __syncthreads();
    const float SC = 0.125f * 1.44269504f;   // 1/sqrt(64) * log2(e)
    #pragma unroll
    for (int c = tid; c < 512; c += 256) {
        const int r = c >> 3, d8 = (c & 7) * 8;
        const size_t src = (size_t)pr[r] * LDQKV + h * HD + d8;
        bf16x8 q = *(const bf16x8*)&qkv[src];
        #pragma unroll
        for (int j = 0; j < 8; j++) q[j] = (__bf16)((float)q[j] * SC);
        *(bf16x8*)&qs[(size_t)(n0 + r) * EDIM + h * HD + d8] = q;
        *(bf16x8*)&ks[(size_t)(n0 + r) * EDIM + h * HD + d8] =
            *(const bf16x8*)&qkv[src + EDIM];
        *(bf16x8*)&T[r][d8] = *(const bf16x8*)&qkv[src + 2 * EDIM];
    }
    __syncthreads();
    #pragma unroll
    for (int c = tid; c < 512; c += 256) {
        const int d = c & 63, k8 = (c >> 6) * 8;
        bf16x8 v;
        #pragma unroll
        for (int j = 0; j < 8; j++) v[j] = T[k8 + j][d];
        *(bf16x8*)&vt[(size_t)(h * HD + d) * N_TOK + n0 + k8] = v;
    }
}

// ---------------- flash attention: BQ=128, sorted, split-K grid, LDS-staged ----------------
// grid (32 qtiles, 8 heads, SPLITK); block 256 = 4 waves; each wave owns two 16-row bands.
__global__ __launch_bounds__(256) void attn_kernel(const __bf16* __restrict__ qs,
                                                   const __bf16* __restrict__ ks,
                                                   const __bf16* __restrict__ vt,
                                                   const int* __restrict__ bs_row,
                                                   const int* __restrict__ qinfo,
                                                   __bf16* __restrict__ po,
                                                   float* __restrict__ pl) {
    __shared__ __attribute__((aligned(16))) __bf16 Ks[BK][72];      // [key][d]
    __shared__ __attribute__((aligned(16))) __bf16 Vs[64][BK + 8];  // [d][key]
    __shared__ __attribute__((aligned(16))) __bf16 Ps[BQ][BK + 8];  // [q][key] wave bands

    const int h = blockIdx.y;
    const int qtile = blockIdx.x;
    const int ck = blockIdx.z;
    const int tid = threadIdx.x, wave = tid >> 6, lane = tid & 63;
    const int lr = lane & 15, lq = lane >> 4;
    const int qb = qtile * BQ;

    const int kt0 = qinfo[qtile * 2];
    const int bs_blockmax = qinfo[qtile * 2 + 1];
    const int nt = (N_TOK - kt0) / BK;
    const int kta = kt0 + ((nt * ck) / SPLITK) * BK;
    const int ktb = kt0 + ((nt * (ck + 1)) / SPLITK) * BK;

    bf16x8 aq[2][2];
    int bs_r[2][4];
    #pragma unroll
    for (int rb = 0; rb < 2; rb++) {
        const __bf16* qrow = qs + (size_t)(qb + rb * 64 + wave * 16 + lr) * EDIM + h * HD;
        aq[rb][0] = *(const bf16x8*)&qrow[lq * 8];
        aq[rb][1] = *(const bf16x8*)&qrow[32 + lq * 8];
        #pragma unroll
        for (int r = 0; r < 4; r++)
            bs_r[rb][r] = bs_row[qb + rb * 64 + wave * 16 + lq * 4 + r];
    }

    float l_i[2][4] = {};
    f32x4 o[2][4] = {};

    const __bf16* kbase = ks + h * HD;
    const __bf16* vbase = vt + (size_t)h * HD * N_TOK;

    const int r0 = tid >> 3, r1 = r0 + 32, k8 = (tid & 7) * 8;
    bf16x8 kr0, kr1, vr0, vr1;
    if (kta < ktb) {
        kr0 = *(const bf16x8*)&kbase[(size_t)(kta + r0) * EDIM + k8];
        kr1 = *(const bf16x8*)&kbase[(size_t)(kta + r1) * EDIM + k8];
        vr0 = *(const bf16x8*)&vbase[(size_t)r0 * N_TOK + kta + k8];
        vr1 = *(const bf16x8*)&vbase[(size_t)r1 * N_TOK + kta + k8];
    }

    for (int kt = kta; kt < ktb; kt += BK) {
        __syncthreads();
        *(bf16x8*)&Ks[r0][k8] = kr0;
        *(bf16x8*)&Ks[r1][k8] = kr1;
        *(bf16x8*)&Vs[r0][k8] = vr0;
        *(bf16x8*)&Vs[r1][k8] = vr1;
        __syncthreads();
        if (kt + BK < ktb) {
            kr0 = *(const bf16x8*)&kbase[(size_t)(kt + BK + r0) * EDIM + k8];
            kr1 = *(const bf16x8*)&kbase[(size_t)(kt + BK + r1) * EDIM + k8];
            vr0 = *(const bf16x8*)&vbase[(size_t)r0 * N_TOK + kt + BK + k8];
            vr1 = *(const bf16x8*)&vbase[(size_t)r1 * N_TOK + kt + BK + k8];
        }

        const bool masked = (kt < bs_blockmax);
        #pragma unroll
        for (int rb = 0; rb < 2; rb++) {
            f32x4 s[4];
            #pragma unroll
            for (int t = 0; t < 4; t++) {
                bf16x8 b0 = *(const bf16x8*)&Ks[t * 16 + lr][lq * 8];
                bf16x8 b1 = *(const bf16x8*)&Ks[t * 16 + lr][32 + lq * 8];
                f32x4 a = {};
                a = __builtin_amdgcn_mfma_f32_16x16x32_bf16(aq[rb][0], b0, a, 0, 0, 0);
                a = __builtin_amdgcn_mfma_f32_16x16x32_bf16(aq[rb][1], b1, a, 0, 0, 0);
                s[t] = a;
            }
            if (masked) {
                #pragma unroll
                for (int t = 0; t < 4; t++) {
                    const int col = kt + t * 16 + lr;
                    #pragma unroll
                    for (int r = 0; r < 4; r++)
                        if (col < bs_r[rb][r]) s[t][r] = -1e9f;
                }
            }
            #pragma unroll
            for (int t = 0; t < 4; t++) {
                #pragma unroll
                for (int r = 0; r < 4; r++) {
                    const float pr = exp2f(s[t][r]);
                    l_i[rb][r] += pr;
                    Ps[rb * 64 + wave * 16 + lq * 4 + r][t * 16 + lr] = (__bf16)pr;
                }
            }
        }
        #pragma unroll
        for (int rb = 0; rb < 2; rb++) {
            #pragma unroll
            for (int ks2 = 0; ks2 < 2; ks2++) {
                bf16x8 ap = *(const bf16x8*)&Ps[rb * 64 + wave * 16 + lr][ks2 * 32 + lq * 8];
                #pragma unroll
                for (int dt = 0; dt < 4; dt++) {
                    bf16x8 bv = *(const bf16x8*)&Vs[dt * 16 + lr][ks2 * 32 + lq * 8];
                    o[rb][dt] = __builtin_amdgcn_mfma_f32_16x16x32_bf16(ap, bv, o[rb][dt], 0, 0, 0);
                }
            }
        }
    }

    #pragma unroll
    for (int rb = 0; rb < 2; rb++) {
        #pragma unroll
        for (int r = 0; r < 4; r++) {
            float v = l_i[rb][r];
            v += __shfl_xor(v, 1);
            v += __shfl_xor(v, 2);
            v += __shfl_xor(v, 4);
            v += __shfl_xor(v, 8);
            l_i[rb][r] = v;
        }
        __bf16* pob = po + (((size_t)(ck * NHEAD + h) * N_TOK) + qb + rb * 64 + wave * 16) * HD;
        #pragma unroll
        for (int dt = 0; dt < 4; dt++)
            #pragma unroll
            for (int r = 0; r < 4; r++)
                pob[(lq * 4 + r) * HD + dt * 16 + lr] = (__bf16)o[rb][dt][r];
        if (lr == 0) {
            #pragma unroll
            for (int r = 0; r < 4; r++)
                pl[(size_t)(ck * NHEAD + h) * N_TOK + qb + rb * 64 + wave * 16 + lq * 4 + r] = l_i[rb][r];
        }
    }
}

// ---------------- combine split-K partials (x4 vectorized), scatter to ctx ----------------
__global__ __launch_bounds__(256) void combine_kernel(const __bf16* __restrict__ po,
                                                      const float* __restrict__ pl,
                                                      const int* __restrict__ perm,
                                                      __bf16* __restrict__ ctx) {
    const int e = blockIdx.x * 256 + threadIdx.x;   // over 4096*128 col4-groups
    const int q = e >> 7;
    const int col = (e & 127) * 4;
    const int h = col >> 6, d = col & 63;
    float s0 = 0.f, s1 = 0.f, s2 = 0.f, s3 = 0.f, l = 0.f;
    #pragma unroll
    for (int c = 0; c < SPLITK; c++) {
        const bf16x4 v = *(const bf16x4*)&po[(((size_t)(c * NHEAD + h) * N_TOK) + q) * HD + d];
        s0 += (float)v[0]; s1 += (float)v[1]; s2 += (float)v[2]; s3 += (float)v[3];
        l += pl[(size_t)(c * NHEAD + h) * N_TOK + q];
    }
    const float rl = 1.0f / l;
    bf16x4 o;
    o[0] = (__bf16)(s0 * rl); o[1] = (__bf16)(s1 * rl);
    o[2] = (__bf16)(s2 * rl); o[3] = (__bf16)(s3 * rl);
    *(bf16x4*)&ctx[(size_t)perm[q] * EDIM + col] = o;
}

// ---------------- fused final GEMM: h = ctx @ weff^T + add2[dmask] + tv[step] ----------------
__global__ __launch_bounds__(256) void gemm_fused(const __bf16* __restrict__ A,
                                                  const __bf16* __restrict__ B,
                                                  const int* __restrict__ dmask,
                                                  const int* __restrict__ steps,
                                                  const float* __restrict__ add2,
                                                  const float* __restrict__ tv,
                                                  float* __restrict__ C) {
    __shared__ __attribute__((aligned(16))) __bf16 As[128][40];
    __shared__ __attribute__((aligned(16))) __bf16 Bs[128][40];
    const int tid = threadIdx.x;
    const int wave = tid >> 6, lane = tid & 63;
    const int wm = (wave >> 1) * 64, wn = (wave & 1) * 64;
    const int bm = blockIdx.x * 128, bn = blockIdx.y * 128;
    const int lr = lane & 15, lq = lane >> 4;

    f32x4 acc[4][4] = {};
    for (int k0 = 0; k0 < EDIM; k0 += 32) {
        __syncthreads();
        #pragma unroll
        for (int c = tid; c < 512; c += 256) {
            const int row = c >> 2, k8 = (c & 3) * 8;
            *(bf16x8*)&As[row][k8] = *(const bf16x8*)&A[(size_t)(bm + row) * EDIM + k0 + k8];
            *(bf16x8*)&Bs[row][k8] = *(const bf16x8*)&B[(size_t)(bn + row) * EDIM + k0 + k8];
        }
        __syncthreads();
        bf16x8 af[4], bfr[4];
        #pragma unroll
        for (int i = 0; i < 4; i++) {
            af[i]  = *(const bf16x8*)&As[wm + i * 16 + lr][lq * 8];
            bfr[i] = *(const bf16x8*)&Bs[wn + i * 16 + lr][lq * 8];
        }
        #pragma unroll
        for (int i = 0; i < 4; i++)
            #pragma unroll
            for (int j = 0; j < 4; j++)
                acc[i][j] = __builtin_amdgcn_mfma_f32_16x16x32_bf16(af[i], bfr[j], acc[i][j], 0, 0, 0);
    }

    int dmr[4][4], str[4][4];
    #pragma unroll
    for (int i = 0; i < 4; i++)
        #pragma unroll
        for (int r = 0; r < 4; r++) {
            const int row = bm + wm + i * 16 + lq * 4 + r;
            dmr[i][r] = dmask[row];
            str[i][r] = min(max(steps[row], 0), NBIN - 1);
        }
    #pragma unroll
    for (int i = 0; i < 4; i++)
        #pragma unroll
        for (int j = 0; j < 4; j++) {
            const int col = bn + wn + j * 16 + lr;
            #pragma unroll
            for (int r = 0; r < 4; r++) {
                const int row = bm + wm + i * 16 + lq * 4 + r;
                C[(size_t)row * EDIM + col] = acc[i][j][r]
                    + add2[dmr[i][r] * EDIM + col] + tv[str[i][r] * EDIM + col];
            }
        }
}

// ---------------- LayerNorm + ReLU + residual ----------------
__global__ __launch_bounds__(256) void ln_kernel(const float* __restrict__ h,
                                                 const float* __restrict__ x,
                                                 const float* __restrict__ gamma,
                                                 const float* __restrict__ beta,
                                                 float* __restrict__ out) {
    const int row = blockIdx.x * 4 + (threadIdx.x >> 6);
    const int lane = threadIdx.x & 63;
    const float* hr = h + (size_t)row * EDIM;
    float4 v0 = ((const float4*)hr)[lane];
    float4 v1 = ((const float4*)hr)[64 + lane];
    float sum = v0.x + v0.y + v0.z + v0.w + v1.x + v1.y + v1.z + v1.w;
    float sq = v0.x * v0.x + v0.y * v0.y + v0.z * v0.z + v0.w * v0.w +
               v1.x * v1.x + v1.y * v1.y + v1.z * v1.z + v1.w * v1.w;
    #pragma unroll
    for (int m = 1; m < 64; m <<= 1) {
        sum += __shfl_xor(sum, m);
        sq  += __shfl_xor(sq, m);
    }
    const float mean = sum * (1.0f / EDIM);
    const float var = sq * (1.0f / EDIM) - mean * mean;
    const float rstd = rsqrtf(var + 1e-5f);
    const float* xr = x + (size_t)row * EDIM;
    float* orow = out + (size_t)row * EDIM;
    #pragma unroll
    for (int half = 0; half < 2; half++) {
        const float4 v = half ? v1 : v0;
        const int cb = half * 256 + lane * 4;
        const float* vp = (const float*)&v;
        float4 res;
        float tmp[4];
        #pragma unroll
        for (int i = 0; i < 4; i++) {
            const int c = cb + i;
            float t = (vp[i] - mean) * rstd * gamma[c] + beta[c];
            t = fmaxf(t, 0.f);
            tmp[i] = xr[c] + t;
        }
        res.x = tmp[0]; res.y = tmp[1]; res.z = tmp[2]; res.w = tmp[3];
        ((float4*)orow)[cb >> 2] = res;
    }
}

// ---------------- launch ----------------
extern "C" void kernel_launch(void* const* d_in, const int* in_sizes, int n_in,
                              void* d_out, int out_size, void* d_ws, size_t ws_size,
                              hipStream_t stream) {
    const float* x      = (const float*)d_in[0];
    const int*   dmask  = (const int*)d_in[1];
    const int*   steps  = (const int*)d_in[2];
    const float* status = (const float*)d_in[3];
    const float* w_in   = (const float*)d_in[4];
    const float* b_in   = (const float*)d_in[5];
    const float* w_out  = (const float*)d_in[6];
    const float* b_out  = (const float*)d_in[7];
    const float* w_mlp  = (const float*)d_in[8];
    const float* b_mlp  = (const float*)d_in[9];
    const float* gamma  = (const float*)d_in[10];
    const float* beta   = (const float*)d_in[11];
    float* out = (float*)d_out;

    char* ws = (char*)d_ws;
    size_t off = 0;
    auto alloc = [&](size_t bytes) {
        void* ptr = ws + off;
        off = (off + bytes + 255) & ~(size_t)255;
        return ptr;
    };
    __bf16* x_bf    = (__bf16*)alloc((size_t)N_TOK * EDIM * 2);   // reused as qs
    __bf16* wqkv_bf = (__bf16*)alloc((size_t)3 * EDIM * EDIM * 2);
    __bf16* wmlp_bf = (__bf16*)alloc((size_t)EDIM * LDCOMB * 2);
    __bf16* woutT_bf= (__bf16*)alloc((size_t)EDIM * EDIM * 2);
    __bf16* weff_bf = (__bf16*)alloc((size_t)EDIM * EDIM * 2);
    __bf16* qkv_bf  = (__bf16*)alloc((size_t)N_TOK * LDQKV * 2);
    __bf16* ks_bf   = (__bf16*)alloc((size_t)N_TOK * EDIM * 2);
    __bf16* vt_bf   = (__bf16*)alloc((size_t)EDIM * N_TOK * 2);
    __bf16* ctx_bf  = (__bf16*)alloc((size_t)N_TOK * EDIM * 2);
    float*  h_f32   = (float*)alloc((size_t)N_TOK * EDIM * 4);
    int*    perm    = (int*)alloc(N_TOK * 4);
    int*    sstep   = (int*)alloc(N_TOK * 4);
    int*    bs_row  = (int*)alloc(N_TOK * 4);
    int*    qinfo   = (int*)alloc(128 * 4);
    __bf16* po      = (__bf16*)alloc((size_t)SPLITK * NHEAD * N_TOK * HD * 2);
    float*  pl      = (float*)alloc((size_t)SPLITK * NHEAD * N_TOK * 4);
    float*  add2    = (float*)alloc(2 * EDIM * 4);
    float*  tv      = (float*)alloc((size_t)NBIN * EDIM * 4);
    __bf16* tmat    = (__bf16*)alloc(128 * 256 * 2);
    __bf16* qs_bf   = x_bf;   // alias: x_bf dead after qkv GEMM

    // prep: converts + w_out^T + add2 + time-matrix + sort/plan
    prep_kernel<<<NB_PREP, 256, 0, stream>>>(
        x, w_in, w_mlp, w_out, status, b_out, b_mlp, steps,
        x_bf, wqkv_bf, wmlp_bf, woutT_bf, add2, tmat, perm, sstep, bs_row, qinfo);
    // qkv GEMM + weff GEMM + tv GEMM (merged)
    gemm2_kernel<<<404, 256, 0, stream>>>(
        x_bf, wqkv_bf, b_in, qkv_bf, wmlp_bf, woutT_bf, weff_bf, tmat, tv);
    // gather sorted Q/K/V^T
    gather_kernel<<<dim3(N_TOK / 64, NHEAD), 256, 0, stream>>>(qkv_bf, perm, qs_bf, ks_bf, vt_bf);
    // attention (BQ=128, split-K grid)
    attn_kernel<<<dim3(N_TOK / BQ, NHEAD, SPLITK), 256, 0, stream>>>(
        qs_bf, ks_bf, vt_bf, bs_row, qinfo, po, pl);
    // combine partials -> ctx (original token order)
    combine_kernel<<<(N_TOK * EDIM) / 1024, 256, 0, stream>>>(po, pl, perm, ctx_bf);
    // h = ctx @ w_eff^T + add2[dmask] + tv[step]
    gemm_fused<<<dim3(N_TOK / 128, EDIM / 128), 256, 0, stream>>>(
        ctx_bf, weff_bf, dmask, steps, add2, tv, h_f32);
    // LN + ReLU + residual
    ln_kernel<<<N_TOK / 4, 256, 0, stream>>>(h_f32, x, gamma, beta, out);
}